// Round 1
// baseline (337.900 us; speedup 1.0000x reference)
//
#include <hip/hip_runtime.h>
#include <math.h>

// Problem constants (from reference setup_inputs)
constexpr int B = 64, T = 2000, C = 100, K = 200, D = 2048;
constexpr float ALPHA = 0.0005f, BETA = 0.2f, LMBD = 1.0f, MARGIN = 100.0f, THRES = 0.5f;

constexpr int KSPLIT = 8;               // feat K split
constexpr int KQ     = K / KSPLIT;      // 25 rows per split

constexpr int GRID = 2048;              // exact fill: 8 blocks/CU on 256 CUs

// sup tiling: 40 t-rows per tile -> 3200 units of 32 KB each
constexpr int SUP_TROWS       = 40;
constexpr int SUP_TILES_PER_B = T / SUP_TROWS;   // 50
constexpr int SUP_UNITS       = B * SUP_TILES_PER_B;  // 3200

// Workspace layout (floats): meanpart [2][KSPLIT][B][D], normsq [2][B],
// ssq [B][C], pos [B][C]
constexpr size_t WS_MEANPART = 0;
constexpr size_t WS_NORMSQ   = (size_t)2 * KSPLIT * B * D;
constexpr size_t WS_SUP_SSQ  = WS_NORMSQ + 2 * B;
constexpr size_t WS_SUP_POS  = WS_SUP_SSQ + (size_t)B * C;

// ---------------------------------------------------------------------------
// feat partial sums: unit u = (tensor, split, dhalf, b); 25 rows x 1024 floats
// ---------------------------------------------------------------------------
__device__ __forceinline__ void do_feat(int u,
                                        const float* __restrict__ feat_act,
                                        const float* __restrict__ feat_bkg,
                                        float* __restrict__ ws) {
    int t = u;
    const int b     = t & 63;  t >>= 6;
    const int dhalf = t & 1;   t >>= 1;
    const int split = t & 7;   t >>= 3;
    const int tensor = t;      // 0 or 1

    const float* __restrict__ feat = (tensor == 0) ? feat_act : feat_bkg;
    const float* p = feat + (size_t)b * K * D + (size_t)split * KQ * D
                     + (size_t)dhalf * 1024 + (size_t)threadIdx.x * 4;

    float4 a0 = make_float4(0.f, 0.f, 0.f, 0.f);
    float4 a1 = make_float4(0.f, 0.f, 0.f, 0.f);
    float4 a2 = make_float4(0.f, 0.f, 0.f, 0.f);
    float4 a3 = make_float4(0.f, 0.f, 0.f, 0.f);

    int k = 0;
    for (; k + 8 <= KQ; k += 8) {
        float4 v0 = *(const float4*)(p + (size_t)(k + 0) * D);
        float4 v1 = *(const float4*)(p + (size_t)(k + 1) * D);
        float4 v2 = *(const float4*)(p + (size_t)(k + 2) * D);
        float4 v3 = *(const float4*)(p + (size_t)(k + 3) * D);
        float4 v4 = *(const float4*)(p + (size_t)(k + 4) * D);
        float4 v5 = *(const float4*)(p + (size_t)(k + 5) * D);
        float4 v6 = *(const float4*)(p + (size_t)(k + 6) * D);
        float4 v7 = *(const float4*)(p + (size_t)(k + 7) * D);
        a0.x += v0.x; a0.y += v0.y; a0.z += v0.z; a0.w += v0.w;
        a1.x += v1.x; a1.y += v1.y; a1.z += v1.z; a1.w += v1.w;
        a2.x += v2.x; a2.y += v2.y; a2.z += v2.z; a2.w += v2.w;
        a3.x += v3.x; a3.y += v3.y; a3.z += v3.z; a3.w += v3.w;
        a0.x += v4.x; a0.y += v4.y; a0.z += v4.z; a0.w += v4.w;
        a1.x += v5.x; a1.y += v5.y; a1.z += v5.z; a1.w += v5.w;
        a2.x += v6.x; a2.y += v6.y; a2.z += v6.z; a2.w += v6.w;
        a3.x += v7.x; a3.y += v7.y; a3.z += v7.z; a3.w += v7.w;
    }
    for (; k < KQ; ++k) {
        float4 v = *(const float4*)(p + (size_t)k * D);
        a0.x += v.x; a0.y += v.y; a0.z += v.z; a0.w += v.w;
    }

    float4 s;
    s.x = (a0.x + a1.x) + (a2.x + a3.x);
    s.y = (a0.y + a1.y) + (a2.y + a3.y);
    s.z = (a0.z + a1.z) + (a2.z + a3.z);
    s.w = (a0.w + a1.w) + (a2.w + a3.w);

    float* dst = ws + WS_MEANPART
                 + ((size_t)((tensor * KSPLIT + split) * B + b)) * D
                 + (size_t)dhalf * 1024 + (size_t)threadIdx.x * 4;
    *(float4*)dst = s;
}

// ---------------------------------------------------------------------------
// sup partials: unit j = (b, 40-row time tile). All threads of the block must
// enter (contains __syncthreads).
// ---------------------------------------------------------------------------
__device__ __forceinline__ void do_sup(int j,
                                       const float* __restrict__ gt,
                                       const float* __restrict__ cas,
                                       float* __restrict__ ws,
                                       float* sh_ssq, float* sh_pos) {
    const int b  = j / SUP_TILES_PER_B;
    const int t0 = (j % SUP_TILES_PER_B) * SUP_TROWS;

    const int tid = threadIdx.x;
    const int c4  = tid % 25;
    const int tl  = tid / 25;          // 0..9 active

    if (tid < C) { sh_ssq[tid] = 0.f; sh_pos[tid] = 0.f; }
    __syncthreads();

    if (tl < 10) {
        const size_t base = ((size_t)b * T + (size_t)(t0 + tl)) * C + (size_t)c4 * 4;

        float4 g[4], q[4];
#pragma unroll
        for (int i = 0; i < 4; ++i) {
            size_t off = base + (size_t)(10 * i) * C;
            g[i] = *(const float4*)(gt + off);
            q[i] = *(const float4*)(cas + off);
        }

        float4 s  = make_float4(0.f, 0.f, 0.f, 0.f);
        float4 pc = make_float4(0.f, 0.f, 0.f, 0.f);

        auto acc = [](float gv, float qv, float& ss, float& pp) {
            float pm = (gv > THRES) ? 1.f : 0.f;
            float dd = qv - pm;
            ss += dd * dd;
            pp += pm;
        };
#pragma unroll
        for (int i = 0; i < 4; ++i) {
            acc(g[i].x, q[i].x, s.x, pc.x);
            acc(g[i].y, q[i].y, s.y, pc.y);
            acc(g[i].z, q[i].z, s.z, pc.z);
            acc(g[i].w, q[i].w, s.w, pc.w);
        }

        const int c = c4 * 4;
        atomicAdd(&sh_ssq[c + 0], s.x);
        atomicAdd(&sh_ssq[c + 1], s.y);
        atomicAdd(&sh_ssq[c + 2], s.z);
        atomicAdd(&sh_ssq[c + 3], s.w);
        atomicAdd(&sh_pos[c + 0], pc.x);
        atomicAdd(&sh_pos[c + 1], pc.y);
        atomicAdd(&sh_pos[c + 2], pc.z);
        atomicAdd(&sh_pos[c + 3], pc.w);
    }
    __syncthreads();

    if (tid < C) {
        atomicAdd(&ws[WS_SUP_SSQ + (size_t)b * C + tid], sh_ssq[tid]);
        atomicAdd(&ws[WS_SUP_POS + (size_t)b * C + tid], sh_pos[tid]);
    }
}

// ---------------------------------------------------------------------------
// Mega kernel, exact-fill persistent grid: 2048 blocks = 8 blocks/CU.
// Block id owns feat unit id plus sup units {id} and {id+2048 if id<1152}.
// Phase order alternates by parity so the feat stream and the gt/cas stream
// stay concurrently live chip-wide.
// ---------------------------------------------------------------------------
__global__ __launch_bounds__(256, 8) void mega_kernel(const float* __restrict__ feat_act,
                                                      const float* __restrict__ feat_bkg,
                                                      const float* __restrict__ gt,
                                                      const float* __restrict__ cas,
                                                      float* __restrict__ ws) {
    const int id = blockIdx.x;

    __shared__ float sh_ssq[C];
    __shared__ float sh_pos[C];

    const bool two_sup = (id + GRID < SUP_UNITS);   // id < 1152

    if (id & 1) {
        do_sup(id, gt, cas, ws, sh_ssq, sh_pos);
        do_feat(id, feat_act, feat_bkg, ws);
        if (two_sup) do_sup(id + GRID, gt, cas, ws, sh_ssq, sh_pos);
    } else {
        do_feat(id, feat_act, feat_bkg, ws);
        do_sup(id, gt, cas, ws, sh_ssq, sh_pos);
        if (two_sup) do_sup(id + GRID, gt, cas, ws, sh_ssq, sh_pos);
    }
}

// ---------------------------------------------------------------------------
// Kernel 2: per-(tensor, b): combine KSPLIT partials, mean (/K), sum sq over D.
// grid = 2*B = 128 blocks, 256 threads.
// ---------------------------------------------------------------------------
__global__ __launch_bounds__(256) void feat_normsq_kernel(const float* __restrict__ ws,
                                                          float* __restrict__ normsq_out) {
    const int tensor = blockIdx.x >> 6;
    const int b      = blockIdx.x & 63;
    const int tid    = threadIdx.x;

    float acc = 0.f;
    const float invK = 1.0f / (float)K;
    for (int d = tid; d < D; d += 256) {
        float m = 0.f;
#pragma unroll
        for (int sp = 0; sp < KSPLIT; ++sp)
            m += ws[WS_MEANPART + ((size_t)((tensor * KSPLIT + sp) * B + b)) * D + d];
        m *= invK;
        acc += m * m;
    }

    __shared__ float sh[256];
    sh[tid] = acc;
    __syncthreads();
    for (int s = 128; s > 0; s >>= 1) {
        if (tid < s) sh[tid] += sh[tid + s];
        __syncthreads();
    }
    if (tid == 0) normsq_out[(size_t)tensor * B + b] = sh[0];
}

// ---------------------------------------------------------------------------
// Kernel 3: final scalar. 1 block, 256 threads, double accumulation.
// ---------------------------------------------------------------------------
__global__ __launch_bounds__(256) void final_kernel(const float* __restrict__ score_act,
                                                    const float* __restrict__ score_bkg,
                                                    const float* __restrict__ label,
                                                    const float* __restrict__ ws,
                                                    float* __restrict__ out) {
    const int tid = threadIdx.x;

    __shared__ float rowsum[B];
    if (tid < B) {
        float s = 0.f;
        const float* row = label + (size_t)tid * C;
        for (int c = 0; c < C; ++c) s += row[c];
        rowsum[tid] = s;
    }
    __syncthreads();

    const float* normsq = ws + WS_NORMSQ;
    const float* ssq_ws = ws + WS_SUP_SSQ;
    const float* pos_ws = ws + WS_SUP_POS;

    double cls = 0.0, be = 0.0, sup = 0.0, cnt = 0.0;
    const float invC = 1.0f / (float)C;
    for (int i = tid; i < B * C; i += 256) {
        int bb = i / C;
        float y = label[i] / rowsum[bb];

        float p   = score_act[i];
        float lp  = fmaxf(logf(p), -100.0f);
        float l1p = fmaxf(logf(1.0f - p), -100.0f);
        cls += (double)(y * lp + (1.0f - y) * l1p);

        float q   = score_bkg[i];
        float lq  = fmaxf(logf(q), -100.0f);
        float l1q = fmaxf(logf(1.0f - q), -100.0f);
        be += (double)(invC * lq + (1.0f - invC) * l1q);

        float pos = pos_ws[i];
        if (pos > 0.5f) {
            sup += (double)sqrtf(ssq_ws[i]);
            cnt += 1.0;
        }
    }

    double um = 0.0;
    if (tid < B) {
        float na = sqrtf(normsq[tid]);
        float nb = sqrtf(normsq[B + tid]);
        float la = fmaxf(MARGIN - na, 0.0f);
        float t  = la + nb;
        um = (double)t * (double)t;
    }

    __shared__ double sd[256];
    auto block_reduce = [&](double v) -> double {
        sd[tid] = v;
        __syncthreads();
        for (int s = 128; s > 0; s >>= 1) {
            if (tid < s) sd[tid] += sd[tid + s];
            __syncthreads();
        }
        double r = sd[0];
        __syncthreads();
        return r;
    };

    double cls_t = block_reduce(cls);
    double be_t  = block_reduce(be);
    double sup_t = block_reduce(sup);
    double cnt_t = block_reduce(cnt);
    double um_t  = block_reduce(um);

    if (tid == 0) {
        double loss_cls = -cls_t / (double)(B * C);
        double loss_be  = -be_t / (double)(B * C);
        double loss_um  = um_t / (double)B;
        double loss_sup = sup_t / cnt_t;
        out[0] = (float)(loss_cls + (double)ALPHA * loss_um +
                         (double)BETA * loss_be + (double)LMBD * loss_sup);
    }
}

extern "C" void kernel_launch(void* const* d_in, const int* in_sizes, int n_in,
                              void* d_out, int out_size, void* d_ws, size_t ws_size,
                              hipStream_t stream) {
    const float* score_act = (const float*)d_in[0];
    const float* score_bkg = (const float*)d_in[1];
    const float* feat_act  = (const float*)d_in[2];
    const float* feat_bkg  = (const float*)d_in[3];
    const float* label     = (const float*)d_in[4];
    const float* gt        = (const float*)d_in[5];
    const float* cas       = (const float*)d_in[6];

    float* ws  = (float*)d_ws;
    float* out = (float*)d_out;

    // zero only the atomic accumulation region (sup ssq + pos)
    hipMemsetAsync(ws + WS_SUP_SSQ, 0, 2 * (size_t)B * C * sizeof(float), stream);

    mega_kernel<<<GRID, 256, 0, stream>>>(feat_act, feat_bkg, gt, cas, ws);
    feat_normsq_kernel<<<2 * B, 256, 0, stream>>>(ws, ws + WS_NORMSQ);
    final_kernel<<<1, 256, 0, stream>>>(score_act, score_bkg, label, ws, out);
}

// Round 3
// 329.026 us; speedup vs baseline: 1.0270x; 1.0270x over previous
//
#include <hip/hip_runtime.h>
#include <math.h>

// Problem constants (from reference setup_inputs)
constexpr int B = 64, T = 2000, C = 100, K = 200, D = 2048;
constexpr float ALPHA = 0.0005f, BETA = 0.2f, LMBD = 1.0f, MARGIN = 100.0f, THRES = 0.5f;

constexpr int KSPLIT = 8;               // feat K split
constexpr int KQ     = K / KSPLIT;      // 25 rows per split

constexpr int GRID = 2048;              // exact fill: 8 blocks/CU on 256 CUs

// sup tiling: 40 t-rows per tile -> 3200 units of 32 KB each
constexpr int SUP_TROWS       = 40;
constexpr int SUP_TILES_PER_B = T / SUP_TROWS;   // 50
constexpr int SUP_UNITS       = B * SUP_TILES_PER_B;  // 3200

// Workspace layout (floats): meanpart [2][KSPLIT][B][D], normsq [2][B],
// ssq [B][C], pos [B][C]
constexpr size_t WS_MEANPART = 0;
constexpr size_t WS_NORMSQ   = (size_t)2 * KSPLIT * B * D;
constexpr size_t WS_SUP_SSQ  = WS_NORMSQ + 2 * B;
constexpr size_t WS_SUP_POS  = WS_SUP_SSQ + (size_t)B * C;

// Non-temporal float4 load: keep the gt/cas stream from evicting feat out of
// the 256 MB Infinity Cache. feat (210 MB) + ws (~19 MB) then stay resident,
// and the bulk of the read traffic returns at cache-hit latency instead of
// ~900 cy HBM latency (the per-CU miss-path cap is what pins us at 2.7 TB/s).
// NOTE: __builtin_nontemporal_load requires a NATIVE vector type, not
// HIP_vector_type — go through ext_vector_type(4).
typedef float floatx4 __attribute__((ext_vector_type(4)));

__device__ __forceinline__ float4 ldnt4(const float* p) {
    floatx4 v = __builtin_nontemporal_load((const floatx4*)p);
    return make_float4(v.x, v.y, v.z, v.w);
}

// ---------------------------------------------------------------------------
// feat partial sums: unit u = (tensor, split, dhalf, b); 25 rows x 1024 floats
// ---------------------------------------------------------------------------
__device__ __forceinline__ void do_feat(int u,
                                        const float* __restrict__ feat_act,
                                        const float* __restrict__ feat_bkg,
                                        float* __restrict__ ws) {
    int t = u;
    const int b     = t & 63;  t >>= 6;
    const int dhalf = t & 1;   t >>= 1;
    const int split = t & 7;   t >>= 3;
    const int tensor = t;      // 0 or 1

    const float* __restrict__ feat = (tensor == 0) ? feat_act : feat_bkg;
    const float* p = feat + (size_t)b * K * D + (size_t)split * KQ * D
                     + (size_t)dhalf * 1024 + (size_t)threadIdx.x * 4;

    float4 a0 = make_float4(0.f, 0.f, 0.f, 0.f);
    float4 a1 = make_float4(0.f, 0.f, 0.f, 0.f);
    float4 a2 = make_float4(0.f, 0.f, 0.f, 0.f);
    float4 a3 = make_float4(0.f, 0.f, 0.f, 0.f);

    int k = 0;
    for (; k + 8 <= KQ; k += 8) {
        float4 v0 = *(const float4*)(p + (size_t)(k + 0) * D);
        float4 v1 = *(const float4*)(p + (size_t)(k + 1) * D);
        float4 v2 = *(const float4*)(p + (size_t)(k + 2) * D);
        float4 v3 = *(const float4*)(p + (size_t)(k + 3) * D);
        float4 v4 = *(const float4*)(p + (size_t)(k + 4) * D);
        float4 v5 = *(const float4*)(p + (size_t)(k + 5) * D);
        float4 v6 = *(const float4*)(p + (size_t)(k + 6) * D);
        float4 v7 = *(const float4*)(p + (size_t)(k + 7) * D);
        a0.x += v0.x; a0.y += v0.y; a0.z += v0.z; a0.w += v0.w;
        a1.x += v1.x; a1.y += v1.y; a1.z += v1.z; a1.w += v1.w;
        a2.x += v2.x; a2.y += v2.y; a2.z += v2.z; a2.w += v2.w;
        a3.x += v3.x; a3.y += v3.y; a3.z += v3.z; a3.w += v3.w;
        a0.x += v4.x; a0.y += v4.y; a0.z += v4.z; a0.w += v4.w;
        a1.x += v5.x; a1.y += v5.y; a1.z += v5.z; a1.w += v5.w;
        a2.x += v6.x; a2.y += v6.y; a2.z += v6.z; a2.w += v6.w;
        a3.x += v7.x; a3.y += v7.y; a3.z += v7.z; a3.w += v7.w;
    }
    for (; k < KQ; ++k) {
        float4 v = *(const float4*)(p + (size_t)k * D);
        a0.x += v.x; a0.y += v.y; a0.z += v.z; a0.w += v.w;
    }

    float4 s;
    s.x = (a0.x + a1.x) + (a2.x + a3.x);
    s.y = (a0.y + a1.y) + (a2.y + a3.y);
    s.z = (a0.z + a1.z) + (a2.z + a3.z);
    s.w = (a0.w + a1.w) + (a2.w + a3.w);

    float* dst = ws + WS_MEANPART
                 + ((size_t)((tensor * KSPLIT + split) * B + b)) * D
                 + (size_t)dhalf * 1024 + (size_t)threadIdx.x * 4;
    *(float4*)dst = s;
}

// ---------------------------------------------------------------------------
// sup partials: unit j = (b, 40-row time tile). All threads of the block must
// enter (contains __syncthreads). gt/cas loads are non-temporal (streaming).
// ---------------------------------------------------------------------------
__device__ __forceinline__ void do_sup(int j,
                                       const float* __restrict__ gt,
                                       const float* __restrict__ cas,
                                       float* __restrict__ ws,
                                       float* sh_ssq, float* sh_pos) {
    const int b  = j / SUP_TILES_PER_B;
    const int t0 = (j % SUP_TILES_PER_B) * SUP_TROWS;

    const int tid = threadIdx.x;
    const int c4  = tid % 25;
    const int tl  = tid / 25;          // 0..9 active

    if (tid < C) { sh_ssq[tid] = 0.f; sh_pos[tid] = 0.f; }
    __syncthreads();

    if (tl < 10) {
        const size_t base = ((size_t)b * T + (size_t)(t0 + tl)) * C + (size_t)c4 * 4;

        float4 g[4], q[4];
#pragma unroll
        for (int i = 0; i < 4; ++i) {
            size_t off = base + (size_t)(10 * i) * C;
            g[i] = ldnt4(gt + off);
            q[i] = ldnt4(cas + off);
        }

        float4 s  = make_float4(0.f, 0.f, 0.f, 0.f);
        float4 pc = make_float4(0.f, 0.f, 0.f, 0.f);

        auto acc = [](float gv, float qv, float& ss, float& pp) {
            float pm = (gv > THRES) ? 1.f : 0.f;
            float dd = qv - pm;
            ss += dd * dd;
            pp += pm;
        };
#pragma unroll
        for (int i = 0; i < 4; ++i) {
            acc(g[i].x, q[i].x, s.x, pc.x);
            acc(g[i].y, q[i].y, s.y, pc.y);
            acc(g[i].z, q[i].z, s.z, pc.z);
            acc(g[i].w, q[i].w, s.w, pc.w);
        }

        const int c = c4 * 4;
        atomicAdd(&sh_ssq[c + 0], s.x);
        atomicAdd(&sh_ssq[c + 1], s.y);
        atomicAdd(&sh_ssq[c + 2], s.z);
        atomicAdd(&sh_ssq[c + 3], s.w);
        atomicAdd(&sh_pos[c + 0], pc.x);
        atomicAdd(&sh_pos[c + 1], pc.y);
        atomicAdd(&sh_pos[c + 2], pc.z);
        atomicAdd(&sh_pos[c + 3], pc.w);
    }
    __syncthreads();

    if (tid < C) {
        atomicAdd(&ws[WS_SUP_SSQ + (size_t)b * C + tid], sh_ssq[tid]);
        atomicAdd(&ws[WS_SUP_POS + (size_t)b * C + tid], sh_pos[tid]);
    }
}

// ---------------------------------------------------------------------------
// Mega kernel, exact-fill persistent grid: 2048 blocks = 8 blocks/CU.
// Block id owns feat unit id plus sup units {id} and {id+2048 if id<1152}.
// Phase order alternates by parity so the feat stream and the gt/cas stream
// stay concurrently live chip-wide.
// ---------------------------------------------------------------------------
__global__ __launch_bounds__(256, 8) void mega_kernel(const float* __restrict__ feat_act,
                                                      const float* __restrict__ feat_bkg,
                                                      const float* __restrict__ gt,
                                                      const float* __restrict__ cas,
                                                      float* __restrict__ ws) {
    const int id = blockIdx.x;

    __shared__ float sh_ssq[C];
    __shared__ float sh_pos[C];

    const bool two_sup = (id + GRID < SUP_UNITS);   // id < 1152

    if (id & 1) {
        do_sup(id, gt, cas, ws, sh_ssq, sh_pos);
        do_feat(id, feat_act, feat_bkg, ws);
        if (two_sup) do_sup(id + GRID, gt, cas, ws, sh_ssq, sh_pos);
    } else {
        do_feat(id, feat_act, feat_bkg, ws);
        do_sup(id, gt, cas, ws, sh_ssq, sh_pos);
        if (two_sup) do_sup(id + GRID, gt, cas, ws, sh_ssq, sh_pos);
    }
}

// ---------------------------------------------------------------------------
// Kernel 2: per-(tensor, b): combine KSPLIT partials, mean (/K), sum sq over D.
// grid = 2*B = 128 blocks, 256 threads.
// ---------------------------------------------------------------------------
__global__ __launch_bounds__(256) void feat_normsq_kernel(const float* __restrict__ ws,
                                                          float* __restrict__ normsq_out) {
    const int tensor = blockIdx.x >> 6;
    const int b      = blockIdx.x & 63;
    const int tid    = threadIdx.x;

    float acc = 0.f;
    const float invK = 1.0f / (float)K;
    for (int d = tid; d < D; d += 256) {
        float m = 0.f;
#pragma unroll
        for (int sp = 0; sp < KSPLIT; ++sp)
            m += ws[WS_MEANPART + ((size_t)((tensor * KSPLIT + sp) * B + b)) * D + d];
        m *= invK;
        acc += m * m;
    }

    __shared__ float sh[256];
    sh[tid] = acc;
    __syncthreads();
    for (int s = 128; s > 0; s >>= 1) {
        if (tid < s) sh[tid] += sh[tid + s];
        __syncthreads();
    }
    if (tid == 0) normsq_out[(size_t)tensor * B + b] = sh[0];
}

// ---------------------------------------------------------------------------
// Kernel 3: final scalar. 1 block, 256 threads, double accumulation.
// ---------------------------------------------------------------------------
__global__ __launch_bounds__(256) void final_kernel(const float* __restrict__ score_act,
                                                    const float* __restrict__ score_bkg,
                                                    const float* __restrict__ label,
                                                    const float* __restrict__ ws,
                                                    float* __restrict__ out) {
    const int tid = threadIdx.x;

    __shared__ float rowsum[B];
    if (tid < B) {
        float s = 0.f;
        const float* row = label + (size_t)tid * C;
        for (int c = 0; c < C; ++c) s += row[c];
        rowsum[tid] = s;
    }
    __syncthreads();

    const float* normsq = ws + WS_NORMSQ;
    const float* ssq_ws = ws + WS_SUP_SSQ;
    const float* pos_ws = ws + WS_SUP_POS;

    double cls = 0.0, be = 0.0, sup = 0.0, cnt = 0.0;
    const float invC = 1.0f / (float)C;
    for (int i = tid; i < B * C; i += 256) {
        int bb = i / C;
        float y = label[i] / rowsum[bb];

        float p   = score_act[i];
        float lp  = fmaxf(logf(p), -100.0f);
        float l1p = fmaxf(logf(1.0f - p), -100.0f);
        cls += (double)(y * lp + (1.0f - y) * l1p);

        float q   = score_bkg[i];
        float lq  = fmaxf(logf(q), -100.0f);
        float l1q = fmaxf(logf(1.0f - q), -100.0f);
        be += (double)(invC * lq + (1.0f - invC) * l1q);

        float pos = pos_ws[i];
        if (pos > 0.5f) {
            sup += (double)sqrtf(ssq_ws[i]);
            cnt += 1.0;
        }
    }

    double um = 0.0;
    if (tid < B) {
        float na = sqrtf(normsq[tid]);
        float nb = sqrtf(normsq[B + tid]);
        float la = fmaxf(MARGIN - na, 0.0f);
        float t  = la + nb;
        um = (double)t * (double)t;
    }

    __shared__ double sd[256];
    auto block_reduce = [&](double v) -> double {
        sd[tid] = v;
        __syncthreads();
        for (int s = 128; s > 0; s >>= 1) {
            if (tid < s) sd[tid] += sd[tid + s];
            __syncthreads();
        }
        double r = sd[0];
        __syncthreads();
        return r;
    };

    double cls_t = block_reduce(cls);
    double be_t  = block_reduce(be);
    double sup_t = block_reduce(sup);
    double cnt_t = block_reduce(cnt);
    double um_t  = block_reduce(um);

    if (tid == 0) {
        double loss_cls = -cls_t / (double)(B * C);
        double loss_be  = -be_t / (double)(B * C);
        double loss_um  = um_t / (double)B;
        double loss_sup = sup_t / cnt_t;
        out[0] = (float)(loss_cls + (double)ALPHA * loss_um +
                         (double)BETA * loss_be + (double)LMBD * loss_sup);
    }
}

extern "C" void kernel_launch(void* const* d_in, const int* in_sizes, int n_in,
                              void* d_out, int out_size, void* d_ws, size_t ws_size,
                              hipStream_t stream) {
    const float* score_act = (const float*)d_in[0];
    const float* score_bkg = (const float*)d_in[1];
    const float* feat_act  = (const float*)d_in[2];
    const float* feat_bkg  = (const float*)d_in[3];
    const float* label     = (const float*)d_in[4];
    const float* gt        = (const float*)d_in[5];
    const float* cas       = (const float*)d_in[6];

    float* ws  = (float*)d_ws;
    float* out = (float*)d_out;

    // zero only the atomic accumulation region (sup ssq + pos)
    (void)hipMemsetAsync(ws + WS_SUP_SSQ, 0, 2 * (size_t)B * C * sizeof(float), stream);

    mega_kernel<<<GRID, 256, 0, stream>>>(feat_act, feat_bkg, gt, cas, ws);
    feat_normsq_kernel<<<2 * B, 256, 0, stream>>>(ws, ws + WS_NORMSQ);
    final_kernel<<<1, 256, 0, stream>>>(score_act, score_bkg, label, ws, out);
}